// Round 7
// baseline (221.075 us; speedup 1.0000x reference)
//
#include <hip/hip_runtime.h>

// PDELoss fused, wave-autonomous, whole-strip-resident version.
// Each 64-lane wave owns one (image, 8-row strip); thread = 4 columns.
// Pay memory latency ONCE per wave: prologue issues ALL strip loads
// (12 pred float4 rows + 8 rhs rows) back-to-back, then a hard
// sched_barrier(0) pins them above the fully-unrolled 10-row register blob:
// dual stencil SL=sum(kl*p), SD=sum(kd*p) with kl/kd in SGPRs
// (readfirstlane; GS = s*SL + (s/r)*SD), horizontal [1,2,1] via shfl,
// vertical [1,2,1]/16 via SSA gh rolls, MSE -> wave reduce -> per-block
// partial -> tiny reduce kernel.
//
// R1-R5: grid fill (null), launch_bounds cap -> spill (reverted), atomic
//     storm removed (65->54us), 2-row unroll (54->50us). Latency exposed
//     every body; ~3 waves/SIMD can't hide it.
// R6: strip-resident attempt FAILED at VGPR=80: compiler SANK the p[12]
//     loads into the blob (full residency needs ~110), re-creating per-row
//     exposure; dual stencil doubled VALU (24->35%) with no latency win.
// R7: pin the schedule. All loads (pred+rhs) issued up front, then
//     __builtin_amdgcn_sched_barrier(0) — scheduler cannot move loads past
//     it. Accept ~110-130 VGPR (4 waves/SIMD tier): enough TLP when each
//     wave stalls ONCE. VGPR count is the fail-check (~80 = barrier didn't
//     bind; >160 / WRITE_SIZE big = spill).

__global__ __launch_bounds__(256)
void pde_loss_kernel(const float* __restrict__ pred,   // [B,256,256]
                     const float* __restrict__ rhs,    // [B,254,254]
                     const float* __restrict__ KL,     // [B,3,3]
                     const float* __restrict__ KD,     // [B,3,3]
                     const float* __restrict__ RR,     // [B,256,256] (col-only)
                     const float* __restrict__ ZZ,     // [B,256,256] (row-only)
                     float* __restrict__ partials)     // [gridDim.x]
{
    constexpr int H = 256, W = 256, OH = 254, OW = 254, SR = 8;
    const int tid = threadIdx.x;
    const int l   = tid & 63;          // lane
    const int wv  = tid >> 6;          // wave in block (0..3)
    const int b   = blockIdx.x >> 3;   // image
    const int strip = (blockIdx.x & 7) * 4 + wv;   // 32 strips of 8 rows
    const int o0 = strip * SR;
    const int o1 = (o0 + SR < OH) ? (o0 + SR) : OH;   // last strip: 6 rows

    const size_t ib = (size_t)b * H * W;
    const float* predb = pred + ib;
    const float* rhsb  = rhs + (size_t)b * OH * OW;
    const int c0 = 4 * l;

    // ---------- issue ALL strip loads up front (MLP, one exposure) ----------
    // pred rows o0-1 .. o0+10 (12 rows); out-of-range rows stay zero.
    float4 p[12];
#pragma unroll
    for (int j = 0; j < 12; ++j) {
        const int row = o0 - 1 + j;
        p[j] = make_float4(0.f, 0.f, 0.f, 0.f);
        if ((unsigned)row < (unsigned)H)
            p[j] = *(const float4*)(predb + (size_t)row * W + c0);
    }
    // all 8 rhs rows now (rows >= o1 stay zero; only last strip has any)
    float2 r0[8], r1[8];
#pragma unroll
    for (int j = 0; j < 8; ++j) {
        r0[j] = make_float2(0.f, 0.f); r1[j] = make_float2(0.f, 0.f);
        if (o0 + j < o1) {
            const float* rr = rhsb + (size_t)(o0 + j) * OW + c0;
            r0[j] = *(const float2*)rr;
            if (c0 + 2 < OW) r1[j] = *(const float2*)(rr + 2);
        }
    }

    // wave-uniform scalars (small loads; also above the fence)
    const float hr  = RR[ib + W + 2] - RR[ib + W + 1];
    const float hz  = ZZ[ib + 2 * W + 1] - ZZ[ib + W + 1];
    float kl[9], kd[9];
#pragma unroll
    for (int t = 0; t < 9; ++t) {
        kl[t] = __int_as_float(__builtin_amdgcn_readfirstlane(__float_as_int(KL[b * 9 + t])));
        kd[t] = __int_as_float(__builtin_amdgcn_readfirstlane(__float_as_int(KD[b * 9 + t])));
    }
    float4 invr;
    invr.x = 1.0f / RR[ib + W + (c0 + 1)];
    invr.y = 1.0f / RR[ib + W + (c0 + 2)];
    invr.z = 1.0f / RR[ib + W + (c0 + 3)];
    invr.w = 1.0f / RR[ib + W + ((c0 + 4 < W) ? (c0 + 4) : (W - 1))];

    // ---------- hard scheduling fence: nothing moves across ----------
    __builtin_amdgcn_sched_barrier(0);

    const float hr2 = hr * hr, hz2 = hz * hz;
    const float s   = -2.0f * (hr2 + hz2) / (hr2 * hz2);

    // per-column combine: GS = s*SL + (s/r)*SD; lane63 z/w (cols 254/255)
    // zeroed via the s4/sir4 fold (kills gs AND lane0's wrap halo).
    const float mzw = (l == 63) ? 0.f : 1.f;
    const float m23 = (c0 + 2 < OW) ? 1.f : 0.f;  // emit cols c0+2,c0+3 valid
    const float m0  = (l > 0) ? 1.f : 0.f;        // left-halo validity
    float4 s4, sir4;
    s4.x = s; s4.y = s; s4.z = s * mzw; s4.w = s * mzw;
    sir4.x = s4.x * invr.x; sir4.y = s4.y * invr.y;
    sir4.z = s4.z * invr.z; sir4.w = s4.w * invr.w;

    // dual-stencil row accumulate: SV += P (*) K[k0..k2] with right-halo nx,ny
#define SROW(SV, P, nx, ny, k0, k1, k2, KC)                                   \
    SV.x = fmaf(P.x, KC[k0], fmaf(P.y, KC[k1], fmaf(P.z, KC[k2], SV.x)));     \
    SV.y = fmaf(P.y, KC[k0], fmaf(P.z, KC[k1], fmaf(P.w, KC[k2], SV.y)));     \
    SV.z = fmaf(P.z, KC[k0], fmaf(P.w, KC[k1], fmaf(nx,  KC[k2], SV.z)));     \
    SV.w = fmaf(P.w, KC[k0], fmaf(nx,  KC[k1], fmaf(ny,  KC[k2], SV.w)));

    // rolling right-halos for pred rows K, K+1 (SSA-renamed in the unroll)
    float ax = __shfl(p[0].x, l + 1, 64), ay = __shfl(p[0].y, l + 1, 64);
    float bx = __shfl(p[1].x, l + 1, 64), by = __shfl(p[1].y, l + 1, 64);
    float4 ghm2 = make_float4(0.f, 0.f, 0.f, 0.f);   // gh row g-2
    float4 ghm1 = make_float4(0.f, 0.f, 0.f, 0.f);   // gh row g-1
    float acc = 0.0f;

#pragma unroll
    for (int K = 0; K < 10; ++K) {
        const int g = o0 - 1 + K;   // GS/gh row index

        // halo for pred row K+2
        const float cx = __shfl(p[K + 2].x, l + 1, 64);
        const float cy = __shfl(p[K + 2].y, l + 1, 64);

        // GS row g: dual stencil + combine (guard is wave-uniform; false -> 0)
        float4 SL = make_float4(0.f, 0.f, 0.f, 0.f);
        float4 SD = make_float4(0.f, 0.f, 0.f, 0.f);
        if (g <= o1 && (unsigned)g < (unsigned)OH) {
            SROW(SL, p[K],     ax, ay, 0, 1, 2, kl)
            SROW(SL, p[K + 1], bx, by, 3, 4, 5, kl)
            SROW(SL, p[K + 2], cx, cy, 6, 7, 8, kl)
            SROW(SD, p[K],     ax, ay, 0, 1, 2, kd)
            SROW(SD, p[K + 1], bx, by, 3, 4, 5, kd)
            SROW(SD, p[K + 2], cx, cy, 6, 7, 8, kd)
        }
        float4 gs;
        gs.x = fmaf(s4.x, SL.x, sir4.x * SD.x);
        gs.y = fmaf(s4.y, SL.y, sir4.y * SD.y);
        gs.z = fmaf(s4.z, SL.z, sir4.z * SD.z);
        gs.w = fmaf(s4.w, SL.w, sir4.w * SD.w);

        // horizontal [1,2,1]
        const float up = __shfl(gs.w, l - 1, 64) * m0;  // lane0 reads lane63: 0
        const float dn = __shfl(gs.x, l + 1, 64);       // lane63: dead via m23
        float4 gh;
        gh.x = fmaf(2.f, gs.x, up   + gs.y);
        gh.y = fmaf(2.f, gs.y, gs.x + gs.z);
        gh.z = fmaf(2.f, gs.z, gs.y + gs.w);
        gh.w = fmaf(2.f, gs.w, gs.z + dn);

        // vertical [1,2,1]/16: emit output row i = g-1
        if (K >= 2) {
            const int i = g - 1;                        // = o0 + K - 2
            if (i < o1) {                               // uniform guard
                const float smx = (ghm2.x + 2.f * ghm1.x + gh.x) * 0.0625f;
                const float smy = (ghm2.y + 2.f * ghm1.y + gh.y) * 0.0625f;
                const float smz = (ghm2.z + 2.f * ghm1.z + gh.z) * 0.0625f;
                const float smw = (ghm2.w + 2.f * ghm1.w + gh.w) * 0.0625f;
                const float dx = smx - r0[K - 2].x;
                const float dy = smy - r0[K - 2].y;
                const float dz = (smz - r1[K - 2].x) * m23;
                const float dw = (smw - r1[K - 2].y) * m23;
                acc = fmaf(dx, dx, acc);
                acc = fmaf(dy, dy, acc);
                acc = fmaf(dz, dz, acc);
                acc = fmaf(dw, dw, acc);
            }
        }

        // SSA rolls (renamed away by the unroll)
        ghm2 = ghm1; ghm1 = gh;
        ax = bx; ay = by; bx = cx; by = cy;
    }
#undef SROW

    // wave reduce -> block partial -> ONE contention-free store per block
#pragma unroll
    for (int off = 32; off > 0; off >>= 1)
        acc += __shfl_down(acc, off, 64);
    __shared__ float wsum[4];
    if (l == 0) wsum[wv] = acc;
    __syncthreads();
    if (tid == 0)
        partials[blockIdx.x] = (wsum[0] + wsum[1]) + (wsum[2] + wsum[3]);
}

// Second stage: reduce N partials -> out (single block). Applies inv_n, so no
// memset dispatch is needed anywhere.
__global__ __launch_bounds__(256)
void reduce_kernel(const float* __restrict__ partials, float* __restrict__ out,
                   int n, float inv_n)
{
    const int tid = threadIdx.x;
    float a = 0.0f;
    for (int i = tid; i < n; i += 256) a += partials[i];
#pragma unroll
    for (int off = 32; off > 0; off >>= 1)
        a += __shfl_down(a, off, 64);
    __shared__ float w[4];
    if ((tid & 63) == 0) w[tid >> 6] = a;
    __syncthreads();
    if (tid == 0) out[0] = ((w[0] + w[1]) + (w[2] + w[3])) * inv_n;
}

extern "C" void kernel_launch(void* const* d_in, const int* in_sizes, int n_in,
                              void* d_out, int out_size, void* d_ws, size_t ws_size,
                              hipStream_t stream) {
    const float* pred = (const float*)d_in[0];
    const float* rhs  = (const float*)d_in[1];
    const float* KL   = (const float*)d_in[2];
    const float* KD   = (const float*)d_in[3];
    const float* RR   = (const float*)d_in[4];
    const float* ZZ   = (const float*)d_in[5];
    // d_in[6] = Gauss kernel [[1,2,1],[2,4,2],[1,2,1]]/16 — hardcoded, separable
    float* out = (float*)d_out;

    const int B = in_sizes[2] / 9;   // 256
    const int nblocks = B * 8;       // 256-thread blocks, 4 strips each
    const float inv_n = 1.0f / ((float)B * 254.0f * 254.0f);

    float* partials = (float*)d_ws;  // nblocks floats
    pde_loss_kernel<<<dim3(nblocks), dim3(256), 0, stream>>>(
        pred, rhs, KL, KD, RR, ZZ, partials);
    reduce_kernel<<<dim3(1), dim3(256), 0, stream>>>(partials, out, nblocks, inv_n);
}

// Round 8
// 213.497 us; speedup vs baseline: 1.0355x; 1.0355x over previous
//
#include <hip/hip_runtime.h>

// PDELoss fused — LDS-staged tile version (R8).
//
// R1-R7 established: (a) time stuck 50-56us across every register-level
// schedule; (b) waves live ~14.6us vs ~2us of VALU -> ~10 global-latency
// exposures/wave; (c) R6+R7 both FAILED to keep the strip register-resident
// (VGPR pinned at 80, compiler sinks loads back to uses; sched_barrier(0)
// didn't bind). Conclusion: the register file can't hold the working set.
// R8: hold it in LDS instead. Block = 4 waves = 32 output rows of one image.
// Stage pred rows rb-1..rb+34 (36 rows x 1KB = 36.9KB) via explicit
// global_load_lds DMA (9 issues/wave, no VGPR, compiler can't sink past the
// barrier) -> ONE latency exposure per block, drained by __syncthreads.
// Waves then read a rolling 3-row window from LDS (ds_read_b128 + _b64,
// ~100cy, hidden under 36 fma/row). Pred halos come straight from LDS
// (no shuffles, no dual-stencil) -> folded per-column c4[9] returns.
// rhs preloaded to regs BEFORE staging: its latency hides under the staging
// drain, and with pred in LDS there is register room for it.
// Only remaining shuffles: gs.w/gs.x horizontal Gauss exchange (2/row).
// Epilogue: per-block partial + tiny reduce kernel (R4 win, kept).
//
// Fail-checks: VGPR ~100-125 (>128 = occupancy tier drop), WRITE_SIZE ~64B
// (MBs = spill), SQ_LDS_BANK_CONFLICT ~0 (float4-coalesced LDS pattern),
// LDS ~37KB (4 blocks/CU).

__device__ __forceinline__ void g2lds16(const float* g, float* l) {
    __builtin_amdgcn_global_load_lds(
        (const __attribute__((address_space(1))) void*)g,
        (__attribute__((address_space(3))) void*)l,
        16 /*bytes, literal*/, 0, 0);
}

__global__ __launch_bounds__(256)
void pde_loss_kernel(const float* __restrict__ pred,   // [B,256,256]
                     const float* __restrict__ rhs,    // [B,254,254]
                     const float* __restrict__ KL,     // [B,3,3]
                     const float* __restrict__ KD,     // [B,3,3]
                     const float* __restrict__ RR,     // [B,256,256] (col-only)
                     const float* __restrict__ ZZ,     // [B,256,256] (row-only)
                     float* __restrict__ partials)     // [gridDim.x]
{
    constexpr int H = 256, W = 256, OH = 254, OW = 254;
    // 36 staged rows + 16-float pad (lane63's b64 halo read off row 35 touches
    // the first 8B past row 35; pad keeps it in-bounds).
    __shared__ float lds[36 * 256 + 16];
    __shared__ float wsum[4];

    const int tid = threadIdx.x;
    const int l   = tid & 63;          // lane
    const int wv  = tid >> 6;          // wave in block (0..3)
    const int b   = blockIdx.x >> 3;   // image
    const int rb  = (blockIdx.x & 7) * 32;        // block's first output row
    const int o0  = rb + wv * 8;                  // wave strip: 8 output rows
    const int o1  = (o0 + 8 < OH) ? (o0 + 8) : OH;
    const int c0  = 4 * l;

    const size_t ib = (size_t)b * H * W;
    const float* predb = pred + ib;
    const float* rhsb  = rhs + (size_t)b * OH * OW;

    // ---- 1) rhs preloads: issued FIRST, land under the staging drain ----
    float2 r0[8], r1[8];
#pragma unroll
    for (int j = 0; j < 8; ++j) {
        r0[j] = make_float2(0.f, 0.f); r1[j] = make_float2(0.f, 0.f);
        if (o0 + j < o1) {
            const float* rr = rhsb + (size_t)(o0 + j) * OW + c0;
            r0[j] = *(const float2*)rr;
            if (c0 + 2 < OW) r1[j] = *(const float2*)(rr + 2);
        }
    }
    // small uniform loads
    const float hr = RR[ib + W + 2] - RR[ib + W + 1];
    const float hz = ZZ[ib + 2 * W + 1] - ZZ[ib + W + 1];
    float klv[9], kdv[9];
#pragma unroll
    for (int t = 0; t < 9; ++t) { klv[t] = KL[b * 9 + t]; kdv[t] = KD[b * 9 + t]; }
    float4 invr;
    invr.x = RR[ib + W + (c0 + 1)];
    invr.y = RR[ib + W + (c0 + 2)];
    invr.z = RR[ib + W + (c0 + 3)];
    invr.w = RR[ib + W + ((c0 + 4 < W) ? (c0 + 4) : (W - 1))];

    // ---- 2) stage pred rows rb-1 .. rb+34 into LDS (DMA, no VGPRs) ----
#pragma unroll
    for (int t = 0; t < 9; ++t) {
        const int j  = wv + 4 * t;          // local row 0..35, wave-uniform
        const int gr = rb - 1 + j;          // global row
        if ((unsigned)gr < (unsigned)H)     // uniform guard; OOB rows unused
            g2lds16(predb + (size_t)gr * W + c0, &lds[j * 256]);
    }

    // ---- 3) fold per-column coefficients while the DMA flies ----
    const float hr2 = hr * hr, hz2 = hz * hz;
    const float s   = -2.0f * (hr2 + hz2) / (hr2 * hz2);
    invr.x = 1.0f / invr.x; invr.y = 1.0f / invr.y;
    invr.z = 1.0f / invr.z; invr.w = 1.0f / invr.w;
    const bool lastl = (l == 63);
    float4 c4[9];
#pragma unroll
    for (int t = 0; t < 9; ++t) {
        const float a = klv[t] * s, d = kdv[t] * s;
        c4[t].x = fmaf(d, invr.x, a);
        c4[t].y = fmaf(d, invr.y, a);
        c4[t].z = lastl ? 0.f : fmaf(d, invr.z, a);   // cols 254/255 dead
        c4[t].w = lastl ? 0.f : fmaf(d, invr.w, a);
    }
    const float m23 = (c0 + 2 < OW) ? 1.f : 0.f;   // emit cols c0+2,c0+3 valid
    const float m0  = (l > 0) ? 1.f : 0.f;         // left-halo validity

    __syncthreads();   // drains global_load_lds (vmcnt0) + joins waves

    // ---- 4) compute: rolling 3-row window read from LDS ----
    const float* ldsw = &lds[wv * 8 * 256];   // wave's row-0 = global o0-1
    float4 p0 = *(const float4*)&ldsw[0 * 256 + c0];
    float4 p1 = *(const float4*)&ldsw[1 * 256 + c0];
    float4 p2 = *(const float4*)&ldsw[2 * 256 + c0];
    float2 h0 = *(const float2*)&ldsw[0 * 256 + c0 + 4];
    float2 h1 = *(const float2*)&ldsw[1 * 256 + c0 + 4];
    float2 h2 = *(const float2*)&ldsw[2 * 256 + c0 + 4];

    float4 ghm2 = make_float4(0.f, 0.f, 0.f, 0.f);
    float4 ghm1 = make_float4(0.f, 0.f, 0.f, 0.f);
    float acc = 0.0f;

#define SROW(P, Hh, t0, t1, t2)                                               \
    gs.x = fmaf(P.x, c4[t0].x, fmaf(P.y, c4[t1].x, fmaf(P.z,  c4[t2].x, gs.x))); \
    gs.y = fmaf(P.y, c4[t0].y, fmaf(P.z, c4[t1].y, fmaf(P.w,  c4[t2].y, gs.y))); \
    gs.z = fmaf(P.z, c4[t0].z, fmaf(P.w, c4[t1].z, fmaf(Hh.x, c4[t2].z, gs.z))); \
    gs.w = fmaf(P.w, c4[t0].w, fmaf(Hh.x, c4[t1].w, fmaf(Hh.y, c4[t2].w, gs.w)));

#pragma unroll
    for (int K = 0; K < 10; ++K) {
        // next window row (row K+3; last needed row is K=8 -> jb+11)
        float4 pr = make_float4(0.f, 0.f, 0.f, 0.f);
        float2 hp = make_float2(0.f, 0.f);
        if (K < 9) {
            pr = *(const float4*)&ldsw[(K + 3) * 256 + c0];
            hp = *(const float2*)&ldsw[(K + 3) * 256 + c0 + 4];
        }

        const int g = o0 - 1 + K;   // GS/gh row
        float4 gs = make_float4(0.f, 0.f, 0.f, 0.f);
        if (g <= o1 && (unsigned)g < (unsigned)OH) {
            SROW(p0, h0, 0, 1, 2)
            SROW(p1, h1, 3, 4, 5)
            SROW(p2, h2, 6, 7, 8)
        }

        // horizontal [1,2,1] (only remaining shuffles)
        const float up = __shfl(gs.w, l - 1, 64) * m0;  // lane0 -> 0
        const float dn = __shfl(gs.x, l + 1, 64);       // lane63 dead via m23
        float4 gh;
        gh.x = fmaf(2.f, gs.x, up   + gs.y);
        gh.y = fmaf(2.f, gs.y, gs.x + gs.z);
        gh.z = fmaf(2.f, gs.z, gs.y + gs.w);
        gh.w = fmaf(2.f, gs.w, gs.z + dn);

        // vertical [1,2,1]/16: emit output row i = g-1
        if (K >= 2) {
            const int i = g - 1;
            if (i < o1) {                                // uniform guard
                const float smx = (ghm2.x + 2.f * ghm1.x + gh.x) * 0.0625f;
                const float smy = (ghm2.y + 2.f * ghm1.y + gh.y) * 0.0625f;
                const float smz = (ghm2.z + 2.f * ghm1.z + gh.z) * 0.0625f;
                const float smw = (ghm2.w + 2.f * ghm1.w + gh.w) * 0.0625f;
                const float dx = smx - r0[K - 2].x;
                const float dy = smy - r0[K - 2].y;
                const float dz = (smz - r1[K - 2].x) * m23;
                const float dw = (smw - r1[K - 2].y) * m23;
                acc = fmaf(dx, dx, acc);
                acc = fmaf(dy, dy, acc);
                acc = fmaf(dz, dz, acc);
                acc = fmaf(dw, dw, acc);
            }
        }

        // rotate (SSA-renamed under full unroll)
        p0 = p1; p1 = p2; p2 = pr;
        h0 = h1; h1 = h2; h2 = hp;
        ghm2 = ghm1; ghm1 = gh;
    }
#undef SROW

    // wave reduce -> block partial -> one contention-free store per block
#pragma unroll
    for (int off = 32; off > 0; off >>= 1)
        acc += __shfl_down(acc, off, 64);
    if (l == 0) wsum[wv] = acc;
    __syncthreads();
    if (tid == 0)
        partials[blockIdx.x] = (wsum[0] + wsum[1]) + (wsum[2] + wsum[3]);
}

// Second stage: reduce N partials -> out (single block). Applies inv_n, so no
// memset dispatch is needed anywhere.
__global__ __launch_bounds__(256)
void reduce_kernel(const float* __restrict__ partials, float* __restrict__ out,
                   int n, float inv_n)
{
    const int tid = threadIdx.x;
    float a = 0.0f;
    for (int i = tid; i < n; i += 256) a += partials[i];
#pragma unroll
    for (int off = 32; off > 0; off >>= 1)
        a += __shfl_down(a, off, 64);
    __shared__ float w[4];
    if ((tid & 63) == 0) w[tid >> 6] = a;
    __syncthreads();
    if (tid == 0) out[0] = ((w[0] + w[1]) + (w[2] + w[3])) * inv_n;
}

extern "C" void kernel_launch(void* const* d_in, const int* in_sizes, int n_in,
                              void* d_out, int out_size, void* d_ws, size_t ws_size,
                              hipStream_t stream) {
    const float* pred = (const float*)d_in[0];
    const float* rhs  = (const float*)d_in[1];
    const float* KL   = (const float*)d_in[2];
    const float* KD   = (const float*)d_in[3];
    const float* RR   = (const float*)d_in[4];
    const float* ZZ   = (const float*)d_in[5];
    // d_in[6] = Gauss kernel [[1,2,1],[2,4,2],[1,2,1]]/16 — hardcoded, separable
    float* out = (float*)d_out;

    const int B = in_sizes[2] / 9;   // 256
    const int nblocks = B * 8;       // 4-wave blocks, 32 output rows each
    const float inv_n = 1.0f / ((float)B * 254.0f * 254.0f);

    float* partials = (float*)d_ws;  // nblocks floats
    pde_loss_kernel<<<dim3(nblocks), dim3(256), 0, stream>>>(
        pred, rhs, KL, KD, RR, ZZ, partials);
    reduce_kernel<<<dim3(1), dim3(256), 0, stream>>>(partials, out, nblocks, inv_n);
}